// Round 1
// baseline (115455.273 us; speedup 1.0000x reference)
//
#include <hip/hip_runtime.h>
#include <stdint.h>

typedef unsigned long long u64;

#define SPS   2048            // samples = time steps per spin
#define NSPIN 32
#define H     512
#define NSTEP (SPS*NSPIN)     // 65536 total recurrence steps
#define TPB   512             // threads per workgroup
#define ROWS  64              // output rows per layer-WG (H / 8)
#define CHK   8               // k-chunks (one per wave)
#define KT    64              // k elements per thread (H / CHK)
#define NL    3

__device__ __forceinline__ u64 ld_agent(const u64* p){
  return __hip_atomic_load(p, __ATOMIC_RELAXED, __HIP_MEMORY_SCOPE_AGENT);
}
__device__ __forceinline__ void st_agent(u64* p, u64 v){
  __hip_atomic_store(p, v, __ATOMIC_RELAXED, __HIP_MEMORY_SCOPE_AGENT);
}
__device__ __forceinline__ unsigned ldu_agent(const unsigned* p){
  return __hip_atomic_load(p, __ATOMIC_RELAXED, __HIP_MEMORY_SCOPE_AGENT);
}
__device__ __forceinline__ void stu_agent(unsigned* p, unsigned v){
  __hip_atomic_store(p, v, __ATOMIC_RELAXED, __HIP_MEMORY_SCOPE_AGENT);
}

// Spin until the 8B packet at p carries `tag` in its high word; return payload.
// Tag rides with the value in one atomic 8B load => no fence needed.
__device__ __forceinline__ float poll_pkt(const u64* p, unsigned tag){
  u64 v = ld_agent(p);
  int guard = 0;
  while ((unsigned)(v >> 32) != tag){
    __builtin_amdgcn_s_sleep(1);
    v = ld_agent(p);
    if (++guard > (1<<22)) break;   // bail instead of hanging the harness
  }
  return __uint_as_float((unsigned)(v & 0xffffffffu));
}

__global__ void init_prog(unsigned* prog){
  prog[threadIdx.x] = 0;            // 512 threads cover 25*16 stride-16 cells
}

__global__ __launch_bounds__(TPB)
void rnn_pipeline(const int* __restrict__ samples,
                  const float* __restrict__ Wih0, const float* __restrict__ Whh0,
                  const float* __restrict__ bih0, const float* __restrict__ bhh0,
                  const float* __restrict__ Wih,  const float* __restrict__ Whh,
                  const float* __restrict__ bih,  const float* __restrict__ bhh,
                  const float* __restrict__ Wd,   const float* __restrict__ bd,
                  float* __restrict__ out,
                  u64* __restrict__ ring, unsigned* __restrict__ prog,
                  int depth)
{
  const int bid = blockIdx.x;
  const int tid = threadIdx.x;
  const int dmask = depth - 1;

  __shared__ float lds_h[2][H];            // staged h(u-1)
  __shared__ float lds_y[2][H];            // staged y_{l-1}(u)  (layers 1,2)
  __shared__ float lds_part[2][CHK][ROWS]; // per-chunk partial dots
  __shared__ float lds_acc[SPS];           // head: per-sample probability product
  __shared__ float lds_red[2][2][8];       // head: per-wave dot partials

  if (bid == 24){
    // ------------------------- head stage -------------------------
    for (int t = tid; t < SPS; t += TPB) lds_acc[t] = 1.0f;
    __syncthreads();
    u64* ring2 = ring + (size_t)2*depth*H;
    const int w = tid >> 6, lane = tid & 63;
    float wd0=0.f, wd1=0.f, b0=0.f, b1=0.f;
    for (int u = 0; u < NSTEP; ++u){
      const int i = u >> 11, t = u & (SPS-1), par = u & 1;
      if ((u & (SPS-1)) == 0){
        wd0 = Wd[((size_t)i*2+0)*H + tid];
        wd1 = Wd[((size_t)i*2+1)*H + tid];
        b0 = bd[i*2+0]; b1 = bd[i*2+1];
      }
      float y = poll_pkt(&ring2[(size_t)(u & dmask)*H + tid], (unsigned)(u+1));
      float p0 = wd0*y, p1 = wd1*y;
      #pragma unroll
      for (int o = 32; o > 0; o >>= 1){
        p0 += __shfl_down(p0, o);
        p1 += __shfl_down(p1, o);
      }
      if (lane == 0){ lds_red[par][0][w] = p0; lds_red[par][1][w] = p1; }
      __syncthreads();
      if (tid == 0){
        float z0 = b0, z1 = b1;
        #pragma unroll
        for (int q = 0; q < 8; ++q){ z0 += lds_red[par][0][q]; z1 += lds_red[par][1][q]; }
        const int sel = samples[t*NSPIN + i];
        const float m  = fmaxf(z0, z1);
        const float e0 = expf(z0 - m), e1 = expf(z1 - m);
        lds_acc[t] *= (sel ? e1 : e0) / (e0 + e1);
      }
      if (((u & 63) == 63) && tid == 0) stu_agent(&prog[bid*16], (unsigned)(u+1));
    }
    if (tid == 0) stu_agent(&prog[bid*16], (unsigned)NSTEP);
    __syncthreads();
    for (int t = tid; t < SPS; t += TPB) out[t] = lds_acc[t];
    return;
  }

  // ------------------------- layer stage -------------------------
  const int layer = bid >> 3, g = bid & 7;
  const int c = tid >> 6, r = tid & 63;        // wave = k-chunk, lane = local row
  const int row = g*ROWS + r;
  u64* ringL  = ring + (size_t)layer*depth*H;
  u64* ringIn = ring + (size_t)(layer > 0 ? layer-1 : 0)*depth*H;
  const bool has_wi = (layer > 0);

  float wh[KT], wi[KT];
  float bsum = 0.f, w0c = 0.f, w1c = 0.f;

  for (int u = 0; u < NSTEP; ++u){
    const int i = u >> 11, t = u & (SPS-1), par = u & 1;

    // per-spin weight/bias reload into registers
    if ((u & (SPS-1)) == 0){
      const float* whp = (layer == 0)
        ? Whh0 + ((size_t)i*H + row)*H + c*KT
        : Whh  + (((size_t)i*(NL-1) + (layer-1))*H + row)*H + c*KT;
      #pragma unroll
      for (int j = 0; j < KT; j += 4){
        float4 v4 = *(const float4*)(whp + j);
        wh[j] = v4.x; wh[j+1] = v4.y; wh[j+2] = v4.z; wh[j+3] = v4.w;
      }
      if (has_wi){
        const float* wip = Wih + (((size_t)i*(NL-1) + (layer-1))*H + row)*H + c*KT;
        #pragma unroll
        for (int j = 0; j < KT; j += 4){
          float4 v4 = *(const float4*)(wip + j);
          wi[j] = v4.x; wi[j+1] = v4.y; wi[j+2] = v4.z; wi[j+3] = v4.w;
        }
      }
      if (c == 0){
        if (layer == 0){
          bsum = bih0[i*H + row] + bhh0[i*H + row];
          w0c  = Wih0[((size_t)i*H + row)*2 + 0];
          w1c  = Wih0[((size_t)i*H + row)*2 + 1];
        } else {
          bsum = bih[((size_t)i*(NL-1) + (layer-1))*H + row]
               + bhh[((size_t)i*(NL-1) + (layer-1))*H + row];
        }
      }
    }

    // ring-overwrite backpressure vs downstream consumers, every 64 steps
    if (((u & 63) == 0) && (u + 64 > depth) && tid == 0){
      const unsigned need = (unsigned)(u + 64 - depth);
      const int cfirst = (layer < 2) ? (layer+1)*8 : 24;
      const int ccount = (layer < 2) ? 8 : 1;
      int guard = 0;
      for (;;){
        unsigned mn = 0xffffffffu;
        for (int q = 0; q < ccount; ++q){
          unsigned pv = ldu_agent(&prog[(cfirst+q)*16]);
          mn = (pv < mn) ? pv : mn;
        }
        if (mn >= need) break;
        __builtin_amdgcn_s_sleep(8);
        if (++guard > (1<<20)) break;
      }
    }

    // poll inputs into LDS (tag rides with value; relaxed is sufficient)
    if (u > 0)
      lds_h[par][tid] = poll_pkt(&ringL[(size_t)((u-1) & dmask)*H + tid], (unsigned)u);
    else
      lds_h[par][tid] = 0.0f;
    if (has_wi)
      lds_y[par][tid] = poll_pkt(&ringIn[(size_t)(u & dmask)*H + tid], (unsigned)(u+1));
    __syncthreads();

    // per-thread partial dot over its k-chunk (wave-uniform LDS addr => broadcast)
    const float* hs = &lds_h[par][c*KT];
    float a0=0.f, a1=0.f, a2=0.f, a3=0.f;
    if (has_wi){
      const float* ys = &lds_y[par][c*KT];
      #pragma unroll
      for (int j = 0; j < KT; j += 4){
        a0 = fmaf(wh[j+0], hs[j+0], a0); a1 = fmaf(wh[j+1], hs[j+1], a1);
        a2 = fmaf(wh[j+2], hs[j+2], a2); a3 = fmaf(wh[j+3], hs[j+3], a3);
        a0 = fmaf(wi[j+0], ys[j+0], a0); a1 = fmaf(wi[j+1], ys[j+1], a1);
        a2 = fmaf(wi[j+2], ys[j+2], a2); a3 = fmaf(wi[j+3], ys[j+3], a3);
      }
    } else {
      #pragma unroll
      for (int j = 0; j < KT; j += 4){
        a0 = fmaf(wh[j+0], hs[j+0], a0); a1 = fmaf(wh[j+1], hs[j+1], a1);
        a2 = fmaf(wh[j+2], hs[j+2], a2); a3 = fmaf(wh[j+3], hs[j+3], a3);
      }
    }
    lds_part[par][c][r] = (a0 + a1) + (a2 + a3);
    __syncthreads();

    // wave 0 finalizes: cross-chunk reduce, bias / one-hot column, tanh, post
    if (c == 0){
      float s = 0.f;
      #pragma unroll
      for (int q = 0; q < CHK; ++q) s += lds_part[par][q][r];
      float add = bsum;
      if (layer == 0 && i > 0){
        const int bit = samples[t*NSPIN + (i-1)];
        add += bit ? w1c : w0c;
      }
      const float hv = tanhf(s + add);
      st_agent(&ringL[(size_t)(u & dmask)*H + row],
               ((u64)(unsigned)(u+1) << 32) | (u64)__float_as_uint(hv));
    }
    if (((u & 63) == 63) && tid == 0) stu_agent(&prog[bid*16], (unsigned)(u+1));
  }
  if (tid == 0) stu_agent(&prog[bid*16], (unsigned)NSTEP);
}

extern "C" void kernel_launch(void* const* d_in, const int* in_sizes, int n_in,
                              void* d_out, int out_size, void* d_ws, size_t ws_size,
                              hipStream_t stream)
{
  const int*   samples = (const int*)  d_in[0];
  const float* Wih0    = (const float*)d_in[1];
  const float* Whh0    = (const float*)d_in[2];
  const float* bih0    = (const float*)d_in[3];
  const float* bhh0    = (const float*)d_in[4];
  const float* Wih     = (const float*)d_in[5];
  const float* Whh     = (const float*)d_in[6];
  const float* bih     = (const float*)d_in[7];
  const float* bhh     = (const float*)d_in[8];
  const float* Wd      = (const float*)d_in[9];
  const float* bd      = (const float*)d_in[10];

  int depth = 256;   // ring depth (steps); shrink if workspace is small
  while (depth > 2 && (size_t)3*depth*H*sizeof(u64) + 4096 > ws_size) depth >>= 1;

  u64*      ring = (u64*)d_ws;
  unsigned* prog = (unsigned*)((char*)d_ws + (size_t)3*depth*H*sizeof(u64));

  init_prog<<<1, 512, 0, stream>>>(prog);
  rnn_pipeline<<<25, TPB, 0, stream>>>(samples, Wih0, Whh0, bih0, bhh0,
                                       Wih, Whh, bih, bhh, Wd, bd,
                                       (float*)d_out, ring, prog, depth);
}